// Round 1
// baseline (78.609 us; speedup 1.0000x reference)
//
#include <hip/hip_runtime.h>
#include <stdint.h>

#define LL   2048
#define DD   256
#define SLOTS 64
#define MN   192
#define PT   8192          // B*L

typedef _Float16 half8 __attribute__((ext_vector_type(8)));
typedef float    f32x4 __attribute__((ext_vector_type(4)));

#define FRAG_ELEMS (MN * DD)   // 49152 f16 elems per frag array

// ---------------- K0: fragment prep ----------------
// mn index is n-major (mn' = n*64 + m) so phase-C selection masks can be built
// with wave ballots (lane = m). aS_h/aS_l: score-GEMM A-frags; bG_h: select-GEMM B-frags.
__global__ __launch_bounds__(256) void prep_kernel(
    const float* __restrict__ mem,
    _Float16* __restrict__ aS_h, _Float16* __restrict__ aS_l,
    _Float16* __restrict__ bG_h)
{
    const int e = blockIdx.x * 256 + threadIdx.x;   // grid 192 -> 49152
    const int mnp = e >> 8;                          // n-major mn index
    const int d   = e & 255;
    const int n = mnp >> 6, m = mnp & 63;
    const float v = mem[((m * 3 + n) << 8) + d];
    const _Float16 h  = (_Float16)v;
    const _Float16 lo = (_Float16)(v - (float)h);

    // score GEMM A-frags: tiles of 16 mn', K-chunks of 32 d
    {
        const int tm = mnp >> 4, r = mnp & 15;
        const int c = d >> 5, q = (d >> 3) & 3, j = d & 7;
        const int i1 = ((tm * 8 + c) * 64 + (q * 16 + r)) * 8 + j;
        aS_h[i1] = h; aS_l[i1] = lo;
    }
    // select GEMM B-frags: K-chunks of 32 mn', d-tiles of 16
    {
        const int c2 = mnp >> 5, q2 = (mnp >> 3) & 3, j2 = mnp & 7;
        const int td = d >> 4, n2 = d & 15;
        const int i2 = ((td * 6 + c2) * 64 + (q2 * 16 + n2)) * 8 + j2;
        bG_h[i2] = h;
    }
}

// ---------------- K1: fused score MFMA + argmax + select MFMA ----------------
// grid 512 x 512 thr (8 waves). Block -> 16 output rows; score window 32 rows.
// Wave split: phase B (pg = w>>2 picks p-tile, tmg = w&3 picks 3 mn-tiles),
// phase C (2 positions/wave, lane = slot m, ballot-built masks),
// phase D (2 d-tiles/wave).
__global__ __launch_bounds__(512, 4) void fused_kernel(
    const float* __restrict__ x, const float* __restrict__ bias,
    const _Float16* __restrict__ aS_h, const _Float16* __restrict__ aS_l,
    const _Float16* __restrict__ bG_h,
    float* __restrict__ out)
{
    __shared__ __align__(16) _Float16 xfh[2 * 8 * 64 * 8];   // 16 KB
    __shared__ __align__(16) _Float16 xfl[2 * 8 * 64 * 8];   // 16 KB
    __shared__ float    scores[MN * 19];       // 14.25 KB, stride 19 (conflict-free C reads)
    __shared__ float    biasS[MN];
    __shared__ uint32_t selS[16 * 8];
    // total ~48 KB -> 2 blocks/CU (grid limit), 16 waves/CU = 4 waves/SIMD

    const int p0   = blockIdx.x * 16;
    const int tid  = threadIdx.x;
    const int lane = tid & 63;
    const int w    = tid >> 6;          // 0..7
    const int q    = lane >> 4, col = lane & 15;
    const int pg   = w >> 2;            // p-tile group (window cols 16*pg..)
    const int tmg  = w & 3;             // mn-tile group (3 tiles each)

    // ---- prefetch phase-B A-frags (c=0) before any barrier (global, no LDS dep) ----
    half8 ah[2][3], al[2][3];
#pragma unroll
    for (int i = 0; i < 3; ++i) {
        const int tm = tmg * 3 + i;
        const size_t off = (size_t)((tm * 8 + 0) * 64 + lane) * 8;
        ah[0][i] = *(const half8*)(aS_h + off);
        al[0][i] = *(const half8*)(aS_l + off);
    }

    if (tid < MN) {
        const int m = tid & 63, n = tid >> 6;
        biasS[tid] = bias[m * 3 + n];    // permute to n-major
    }

    // ---- Phase A: stage x window -> f16 hi/lo B-frags in LDS ----
    {
        const int rr = tid >> 4;        // window row 0..31
        const int dc = tid & 15;        // 16-d chunk
        int g = p0 - 2 + rr;
        g = g < 0 ? 0 : (g > PT - 1 ? PT - 1 : g);
        const float4* xr = (const float4*)(x + (size_t)g * DD + dc * 16);
        const int pt = rr >> 4, lr = rr & 15;
        const int c  = dc >> 1, h = dc & 1;
#pragma unroll
        for (int s = 0; s < 2; ++s) {   // q = 2h + s
            const float4 u = xr[s * 2];
            const float4 v = xr[s * 2 + 1];
            float f[8] = {u.x, u.y, u.z, u.w, v.x, v.y, v.z, v.w};
            half8 hi, lo;
#pragma unroll
            for (int j = 0; j < 8; ++j) {
                const _Float16 hh = (_Float16)f[j];
                hi[j] = hh;
                lo[j] = (_Float16)(f[j] - (float)hh);
            }
            const int base = ((pt * 8 + c) * 64 + (2 * h + s) * 16 + lr) * 8;
            *(half8*)(xfh + base) = hi;
            *(half8*)(xfl + base) = lo;
        }
    }
    __syncthreads();

    // ---- Phase B: score GEMM, depth-1 pipelined over c ----
    {
        f32x4 acc[3];
#pragma unroll
        for (int i = 0; i < 3; ++i) acc[i] = (f32x4){0.f, 0.f, 0.f, 0.f};

        half8 bh[2], bl[2];
        {
            const int base = ((pg * 8 + 0) * 64 + lane) * 8;
            bh[0] = *(const half8*)(xfh + base);
            bl[0] = *(const half8*)(xfl + base);
        }

#pragma unroll
        for (int c = 0; c < 8; ++c) {
            const int cur = c & 1, nxt = cur ^ 1;
            if (c < 7) {
#pragma unroll
                for (int i = 0; i < 3; ++i) {
                    const int tm = tmg * 3 + i;
                    const size_t off = (size_t)((tm * 8 + c + 1) * 64 + lane) * 8;
                    ah[nxt][i] = *(const half8*)(aS_h + off);
                    al[nxt][i] = *(const half8*)(aS_l + off);
                }
                const int base = ((pg * 8 + c + 1) * 64 + lane) * 8;
                bh[nxt] = *(const half8*)(xfh + base);
                bl[nxt] = *(const half8*)(xfl + base);
            }
#pragma unroll
            for (int i = 0; i < 3; ++i) {
                acc[i] = __builtin_amdgcn_mfma_f32_16x16x32_f16(ah[cur][i], bh[cur], acc[i], 0, 0, 0);
                acc[i] = __builtin_amdgcn_mfma_f32_16x16x32_f16(ah[cur][i], bl[cur], acc[i], 0, 0, 0);
                acc[i] = __builtin_amdgcn_mfma_f32_16x16x32_f16(al[cur][i], bh[cur], acc[i], 0, 0, 0);
            }
        }

        // store scores; only window cols 0..17 needed
        const int wp = pg * 16 + col;
#pragma unroll
        for (int i = 0; i < 3; ++i) {
            const int tm = tmg * 3 + i;
            if (wp < 18) {
#pragma unroll
                for (int r = 0; r < 4; ++r)
                    scores[(tm * 16 + q * 4 + r) * 19 + wp] = acc[i][r];
            }
        }
    }

    // ---- prefetch phase-D B-frags (c=0) before the barrier ----
    half8 mg[2][2];
#pragma unroll
    for (int i = 0; i < 2; ++i) {
        const int td = w * 2 + i;
        const size_t off = (size_t)((td * 6 + 0) * 64 + lane) * 8;
        mg[0][i] = *(const half8*)(bG_h + off);
    }
    __syncthreads();

    // ---- Phase C: wave-parallel argmax (lane = slot m) + ballot mask build ----
#pragma unroll
    for (int it = 0; it < 2; ++it) {
        const int pl = w * 2 + it;
        const int m  = lane;
        const int p  = p0 + pl;
        const int l  = p & (LL - 1);
        const float v0 = ((l >= 2) ? scores[(      m) * 19 + pl + 0] : 0.f) + biasS[      m];
        const float v1 = ((l >= 1) ? scores[( 64 + m) * 19 + pl + 1] : 0.f) + biasS[ 64 + m];
        const float v2 =             scores[(128 + m) * 19 + pl + 2]        + biasS[128 + m];
        int bn = 0; float bv = v0;
        if (v1 > bv) { bv = v1; bn = 1; }
        if (v2 > bv) { bv = v2; bn = 2; }
        const unsigned long long b0 = __ballot(bn == 0);
        const unsigned long long b1 = __ballot(bn == 1);
        const unsigned long long b2 = __ballot(bn == 2);
        if (lane < 6) {
            const unsigned long long B = (lane >> 1) == 0 ? b0 : ((lane >> 1) == 1 ? b1 : b2);
            selS[pl * 8 + lane] = (uint32_t)(B >> ((lane & 1) * 32));
        }
    }
    __syncthreads();

    // ---- Phase D: select GEMM (f16 hi only), depth-1 pipelined ----
    {
        uint32_t sw[6];
#pragma unroll
        for (int c = 0; c < 6; ++c) sw[c] = selS[col * 8 + c];

        f32x4 acc2[2];
#pragma unroll
        for (int i = 0; i < 2; ++i) acc2[i] = (f32x4){0.f, 0.f, 0.f, 0.f};

        const _Float16 ONE = (_Float16)1.f, ZERO = (_Float16)0.f;
        const int qb = q * 8;
#pragma unroll
        for (int c = 0; c < 6; ++c) {
            const int cur = c & 1, nxt = cur ^ 1;
            if (c < 5) {
#pragma unroll
                for (int i = 0; i < 2; ++i) {
                    const int td = w * 2 + i;
                    const size_t off = (size_t)((td * 6 + c + 1) * 64 + lane) * 8;
                    mg[nxt][i] = *(const half8*)(bG_h + off);
                }
            }
            half8 sel;
#pragma unroll
            for (int j = 0; j < 8; ++j)
                sel[j] = ((sw[c] >> (qb + j)) & 1u) ? ONE : ZERO;
#pragma unroll
            for (int i = 0; i < 2; ++i)
                acc2[i] = __builtin_amdgcn_mfma_f32_16x16x32_f16(sel, mg[cur][i], acc2[i], 0, 0, 0);
        }

#pragma unroll
        for (int i = 0; i < 2; ++i) {
            const int td = w * 2 + i;
#pragma unroll
            for (int r = 0; r < 4; ++r)
                out[(size_t)(p0 + q * 4 + r) * DD + td * 16 + col] = acc2[i][r];
        }
    }
}

extern "C" void kernel_launch(void* const* d_in, const int* in_sizes, int n_in,
                              void* d_out, int out_size, void* d_ws, size_t ws_size,
                              hipStream_t stream) {
    (void)in_sizes; (void)n_in; (void)out_size; (void)ws_size;
    const float* x    = (const float*)d_in[0];
    const float* mem  = (const float*)d_in[1];
    const float* bias = (const float*)d_in[2];
    float* out = (float*)d_out;

    _Float16* aS_h = (_Float16*)d_ws;
    _Float16* aS_l = aS_h + FRAG_ELEMS;
    _Float16* bG_h = aS_l + FRAG_ELEMS;

    prep_kernel<<<FRAG_ELEMS / 256, 256, 0, stream>>>(mem, aS_h, aS_l, bG_h);
    fused_kernel<<<PT / 16, 512, 0, stream>>>(x, bias, aS_h, aS_l, bG_h, out);
}

// Round 2
// 73.323 us; speedup vs baseline: 1.0721x; 1.0721x over previous
//
#include <hip/hip_runtime.h>
#include <stdint.h>

#define LL   2048
#define DD   256
#define SLOTS 64
#define MN   192
#define PT   8192          // B*L

typedef _Float16 half8 __attribute__((ext_vector_type(8)));
typedef float    f32x4 __attribute__((ext_vector_type(4)));

#define FRAG_ELEMS (MN * DD)   // 49152 f16 elems per frag array

// ---------------- K0: fragment prep ----------------
// mn index is n-major (mn' = n*64 + m) so phase-C selection masks can be built
// with wave ballots (lane = m). aS_h/aS_l: score-GEMM A-frags; bG_h: select-GEMM B-frags.
__global__ __launch_bounds__(256) void prep_kernel(
    const float* __restrict__ mem,
    _Float16* __restrict__ aS_h, _Float16* __restrict__ aS_l,
    _Float16* __restrict__ bG_h)
{
    const int e = blockIdx.x * 256 + threadIdx.x;   // grid 192 -> 49152
    const int mnp = e >> 8;                          // n-major mn index
    const int d   = e & 255;
    const int n = mnp >> 6, m = mnp & 63;
    const float v = mem[((m * 3 + n) << 8) + d];
    const _Float16 h  = (_Float16)v;
    const _Float16 lo = (_Float16)(v - (float)h);

    // score GEMM A-frags: tiles of 16 mn', K-chunks of 32 d
    {
        const int tm = mnp >> 4, r = mnp & 15;
        const int c = d >> 5, q = (d >> 3) & 3, j = d & 7;
        const int i1 = ((tm * 8 + c) * 64 + (q * 16 + r)) * 8 + j;
        aS_h[i1] = h; aS_l[i1] = lo;
    }
    // select GEMM B-frags: K-chunks of 32 mn', d-tiles of 16
    {
        const int c2 = mnp >> 5, q2 = (mnp >> 3) & 3, j2 = mnp & 7;
        const int td = d >> 4, n2 = d & 15;
        const int i2 = ((td * 6 + c2) * 64 + (q2 * 16 + n2)) * 8 + j2;
        bG_h[i2] = h;
    }
}

// ---------------- K1: fused score MFMA + argmax + select MFMA ----------------
// grid 256 x 768 thr (12 waves). Block -> 32 output rows; 48-slot window (34 real).
// Phase B: wave w owns tm-tile w (A-frags read ONCE per CU), all 3 p-tiles.
// Phase C: pl = w, w+12, w+24 (ballot masks, lane = slot m).
// Phase D: tasks t = w, w+12, w+24 over (pt, td).
__global__ __launch_bounds__(768, 3) void fused_kernel(
    const float* __restrict__ x, const float* __restrict__ bias,
    const _Float16* __restrict__ aS_h, const _Float16* __restrict__ aS_l,
    const _Float16* __restrict__ bG_h,
    float* __restrict__ out)
{
    __shared__ __align__(16) _Float16 xfh[3 * 8 * 64 * 8];   // 24 KB
    __shared__ __align__(16) _Float16 xfl[3 * 8 * 64 * 8];   // 24 KB
    __shared__ float    scores[MN * 35];       // 26.25 KB, stride 35 (3m mod 32 distinct)
    __shared__ float    biasS[MN];
    __shared__ uint32_t selS[32 * 8];
    // total ~76 KB, 1 block/CU (grid == 256)

    const int p0   = blockIdx.x * 32;
    const int tid  = threadIdx.x;
    const int lane = tid & 63;
    const int w    = tid >> 6;          // 0..11
    const int q    = lane >> 4, col = lane & 15;
    const int tm   = w;                 // mn-tile owned by this wave

    // ---- prefetch phase-B A-frags (c=0) before any barrier ----
    half8 ah[2], al[2];
    {
        const size_t off = (size_t)((tm * 8 + 0) * 64 + lane) * 8;
        ah[0] = *(const half8*)(aS_h + off);
        al[0] = *(const half8*)(aS_l + off);
    }

    if (tid < MN) {
        const int m = tid & 63, n = tid >> 6;
        biasS[tid] = bias[m * 3 + n];    // permute to n-major
    }

    // ---- Phase A: stage 48-slot x window -> f16 hi/lo B-frags in LDS ----
    // slot rr holds global row clamp(p0-2+rr); only slots 0..33 are consumed.
#pragma unroll
    for (int k = 0; k < 2; ++k) {
        const int idx = tid + k * 768;  // 0..1535
        const int rr  = idx >> 5;       // slot 0..47
        const int ch  = idx & 31;       // 8-d chunk
        int g = p0 - 2 + rr;
        g = g < 0 ? 0 : (g > PT - 1 ? PT - 1 : g);
        const float4* xr = (const float4*)(x + (size_t)g * DD + ch * 8);
        const float4 u = xr[0];
        const float4 v = xr[1];
        float f[8] = {u.x, u.y, u.z, u.w, v.x, v.y, v.z, v.w};
        half8 hi, lo;
#pragma unroll
        for (int j = 0; j < 8; ++j) {
            const _Float16 hh = (_Float16)f[j];
            hi[j] = hh;
            lo[j] = (_Float16)(f[j] - (float)hh);
        }
        const int c = ch >> 2, qq = ch & 3;
        const int pt = rr >> 4, lr = rr & 15;
        const int base = ((pt * 8 + c) * 64 + qq * 16 + lr) * 8;
        *(half8*)(xfh + base) = hi;
        *(half8*)(xfl + base) = lo;
    }
    __syncthreads();

    // ---- Phase B: score GEMM, A-frags once per wave, 3 p-tiles ----
    {
        f32x4 acc[3];
#pragma unroll
        for (int p = 0; p < 3; ++p) acc[p] = (f32x4){0.f, 0.f, 0.f, 0.f};

        half8 bh[2][3], bl[2][3];
#pragma unroll
        for (int p = 0; p < 3; ++p) {
            const int base = ((p * 8 + 0) * 64 + lane) * 8;
            bh[0][p] = *(const half8*)(xfh + base);
            bl[0][p] = *(const half8*)(xfl + base);
        }

#pragma unroll
        for (int c = 0; c < 8; ++c) {
            const int cur = c & 1, nxt = cur ^ 1;
            if (c < 7) {
                const size_t off = (size_t)((tm * 8 + c + 1) * 64 + lane) * 8;
                ah[nxt] = *(const half8*)(aS_h + off);
                al[nxt] = *(const half8*)(aS_l + off);
#pragma unroll
                for (int p = 0; p < 3; ++p) {
                    const int base = ((p * 8 + c + 1) * 64 + lane) * 8;
                    bh[nxt][p] = *(const half8*)(xfh + base);
                    bl[nxt][p] = *(const half8*)(xfl + base);
                }
            }
#pragma unroll
            for (int p = 0; p < 3; ++p) {
                acc[p] = __builtin_amdgcn_mfma_f32_16x16x32_f16(ah[cur], bh[cur][p], acc[p], 0, 0, 0);
                acc[p] = __builtin_amdgcn_mfma_f32_16x16x32_f16(ah[cur], bl[cur][p], acc[p], 0, 0, 0);
                acc[p] = __builtin_amdgcn_mfma_f32_16x16x32_f16(al[cur], bh[cur][p], acc[p], 0, 0, 0);
            }
        }

        // store scores; window cols 0..33 needed
#pragma unroll
        for (int p = 0; p < 3; ++p) {
            const int wp = p * 16 + col;
            if (wp < 34) {
#pragma unroll
                for (int r = 0; r < 4; ++r)
                    scores[(tm * 16 + q * 4 + r) * 35 + wp] = acc[p][r];
            }
        }
    }

    // ---- prefetch phase-D first task (t=w -> pt=0, td=w) c=0 before the barrier ----
    half8 mg[2];
    mg[0] = *(const half8*)(bG_h + (size_t)((w * 6 + 0) * 64 + lane) * 8);
    __syncthreads();

    // ---- Phase C: wave-parallel argmax (lane = slot m) + ballot mask build ----
    for (int pl = w; pl < 32; pl += 12) {
        const int m = lane;
        const int p = p0 + pl;
        const int l = p & (LL - 1);
        const float v0 = ((l >= 2) ? scores[(      m) * 35 + pl + 0] : 0.f) + biasS[      m];
        const float v1 = ((l >= 1) ? scores[( 64 + m) * 35 + pl + 1] : 0.f) + biasS[ 64 + m];
        const float v2 =             scores[(128 + m) * 35 + pl + 2]        + biasS[128 + m];
        int bn = 0; float bv = v0;
        if (v1 > bv) { bv = v1; bn = 1; }
        if (v2 > bv) { bv = v2; bn = 2; }
        const unsigned long long b0 = __ballot(bn == 0);
        const unsigned long long b1 = __ballot(bn == 1);
        const unsigned long long b2 = __ballot(bn == 2);
        if (lane < 6) {
            const unsigned long long B = (lane >> 1) == 0 ? b0 : ((lane >> 1) == 1 ? b1 : b2);
            selS[pl * 8 + lane] = (uint32_t)(B >> ((lane & 1) * 32));
        }
    }
    __syncthreads();

    // ---- Phase D: select GEMM (f16 hi only), tasks t = w, w+12, w+24 ----
    {
        const _Float16 ONE = (_Float16)1.f, ZERO = (_Float16)0.f;
        const int qb = q * 8;
#pragma unroll
        for (int ti = 0; ti < 3; ++ti) {
            const int t = w + ti * 12;
            if (t < 32) {
                const int pt = t >> 4, td = t & 15;
                uint32_t sw[6];
#pragma unroll
                for (int c = 0; c < 6; ++c) sw[c] = selS[(pt * 16 + col) * 8 + c];

                f32x4 acc2 = (f32x4){0.f, 0.f, 0.f, 0.f};
#pragma unroll
                for (int c = 0; c < 6; ++c) {
                    const int cur = c & 1, nxt = cur ^ 1;   // par resets each task (6 steps = even)
                    // prefetch next (same task c+1, or next task c=0)
                    if (c < 5) {
                        mg[nxt] = *(const half8*)(bG_h + (size_t)((td * 6 + c + 1) * 64 + lane) * 8);
                    } else {
                        const int tn = t + 12;
                        if (tn < 32) {
                            const int tdn = tn & 15;
                            mg[nxt] = *(const half8*)(bG_h + (size_t)((tdn * 6 + 0) * 64 + lane) * 8);
                        }
                    }
                    half8 sel;
#pragma unroll
                    for (int j = 0; j < 8; ++j)
                        sel[j] = ((sw[c] >> (qb + j)) & 1u) ? ONE : ZERO;
                    acc2 = __builtin_amdgcn_mfma_f32_16x16x32_f16(sel, mg[cur], acc2, 0, 0, 0);
                }

#pragma unroll
                for (int r = 0; r < 4; ++r)
                    out[(size_t)(p0 + pt * 16 + q * 4 + r) * DD + td * 16 + col] = acc2[r];
            }
        }
    }
}

extern "C" void kernel_launch(void* const* d_in, const int* in_sizes, int n_in,
                              void* d_out, int out_size, void* d_ws, size_t ws_size,
                              hipStream_t stream) {
    (void)in_sizes; (void)n_in; (void)out_size; (void)ws_size;
    const float* x    = (const float*)d_in[0];
    const float* mem  = (const float*)d_in[1];
    const float* bias = (const float*)d_in[2];
    float* out = (float*)d_out;

    _Float16* aS_h = (_Float16*)d_ws;
    _Float16* aS_l = aS_h + FRAG_ELEMS;
    _Float16* bG_h = aS_l + FRAG_ELEMS;

    prep_kernel<<<FRAG_ELEMS / 256, 256, 0, stream>>>(mem, aS_h, aS_l, bG_h);
    fused_kernel<<<PT / 32, 768, 0, stream>>>(x, bias, aS_h, aS_l, bG_h, out);
}